// Round 11
// baseline (6871.421 us; speedup 1.0000x reference)
//
#include <hip/hip_runtime.h>

// FPS: B=64, N=32768, C=3, S=1024. One block per batch.
//
// Round-11: bit-exact spatial culling. Full-scan variants (R3-R10) plateau
// at ~3.8us/step: 256KB/step re-streamed through 32KB L1 + serial reduce
// tail, with only 4 waves/SIMD to hide latency. Fix: 512 grid cells (8^3);
// min_d lives in LDS; per-cell cached max-key (u64 = val_bits<<32 | ~idx)
// + winner coords. A cell is skipped iff lb2(p, cellbox) >= bmax*1.000004:
// then every member has computed d >= min_d, so fminf leaves min_d
// bit-identical and the cached key stays exact (margin 4e-6 >> total f32
// rounding error ~6e-7 of the lb2/d computations). Dirty cells rescanned by
// their owner wave; global argmax = scan of 512 cached keys with coords
// carried through the reduction -> no global loads in the serial chain.
//
// Exactness (validated rounds 3-10): d = fma(dz,dz, fma(dx,dx, dy*dy)),
// fminf running min, first-occurrence argmax via u64 keys (~idx tie-break,
// order-independent). Culling only skips provably-no-op updates.

typedef unsigned long long u64;
typedef unsigned int u32;
typedef unsigned short u16;

#define FPS_N   32768
#define FPS_S   1024
#define FPS_NT  1024
#define NCELL   512            // 8x8x8
#define PPT     (FPS_N / FPS_NT)

__device__ __forceinline__ int bin_of(float v) {
    int i = (int)(v * 8.0f);
    i = i < 0 ? 0 : (i > 7 ? 7 : i);
    // fix-up so the point provably lies in [i*0.125, (i+1)*0.125]
    if (v < (float)i * 0.125f) --i;
    if (v >= (float)(i + 1) * 0.125f) ++i;
    i = i < 0 ? 0 : (i > 7 ? 7 : i);
    return i;
}

__global__ __launch_bounds__(FPS_NT) void FPSModel_80753975099708_kernel(
    const float* __restrict__ x,   // [B, N, 3]
    float* __restrict__ out_pts,   // [B, S, 3]
    float* __restrict__ out_idx,   // [B, S] (indices as float values)
    u16* __restrict__ ids_ws)      // [B][N] cell-sorted point ids
{
#pragma clang fp contract(off)
    const int b = blockIdx.x;
    const int t = threadIdx.x;
    const int w = t >> 6;
    const int lane = t & 63;
    const float* __restrict__ xb = x + (size_t)b * FPS_N * 3;
    float* __restrict__ op = out_pts + (size_t)b * FPS_S * 3;
    float* __restrict__ oi = out_idx + (size_t)b * FPS_S;
    u16* __restrict__ ids = ids_ws + (size_t)b * FPS_N;

    __shared__ float mind[FPS_N];        // 131072 B
    __shared__ u32  cellCnt[NCELL];      // 2048 B (hist, then scatter cursor)
    __shared__ u32  cellStart[NCELL + 1];// 2052 B
    __shared__ u64  bkey[NCELL];         // 4096 B
    __shared__ float bwx[NCELL], bwy[NCELL], bwz[NCELL]; // 6144 B
    __shared__ u64  redk[16];            // 128 B
    __shared__ float redx[16], redy[16], redz[16];       // 192 B

    // ---- Prologue: bucket the cloud (counting sort of ids into ws) ----
    if (t < NCELL) { cellCnt[t] = 0; bwx[t] = 0.f; bwy[t] = 0.f; bwz[t] = 0.f; }
    __syncthreads();

    int cellr[PPT];
#pragma unroll
    for (int k = 0; k < PPT; ++k) {
        const int i = k * FPS_NT + t;
        const float gx = xb[3 * i], gy = xb[3 * i + 1], gz = xb[3 * i + 2];
        cellr[k] = (bin_of(gx) << 6) | (bin_of(gy) << 3) | bin_of(gz);
        mind[i] = __int_as_float(0x7f800000);   // +inf
        atomicAdd(&cellCnt[cellr[k]], 1u);
    }
    __syncthreads();

    if (t == 0) {
        u32 acc = 0;
        for (int c = 0; c < NCELL; ++c) { cellStart[c] = acc; acc += cellCnt[c]; }
        cellStart[NCELL] = acc;                 // == FPS_N
    }
    __syncthreads();
    if (t < NCELL) cellCnt[t] = cellStart[t];   // scatter cursor
    __syncthreads();
#pragma unroll
    for (int k = 0; k < PPT; ++k) {
        const u32 slot = atomicAdd(&cellCnt[cellr[k]], 1u);
        ids[slot] = (u16)(k * FPS_NT + t);
    }
    if (t < NCELL) {
        bkey[t] = (cellStart[t + 1] > cellStart[t])
                      ? 0x7f80000000000000ULL   // +inf value, forces dirty
                      : 0ULL;                   // empty cell: never dirty/wins
    }

    // ---- Seed: point 0 ----
    float px = xb[0], py = xb[1], pz = xb[2];
    if (t == 0) {
        oi[0] = 0.0f;
        op[0] = px; op[1] = py; op[2] = pz;
    }
    __syncthreads();

    for (int s = 1; s < FPS_S; ++s) {
        // ---- PHASE A: cull + update owned dirty cells ----
        bool dirty = false;
        if (lane < 32) {
            const int c = (lane << 4) + w;      // wave w owns cells w, w+16, ...
            const int ix = (c >> 6) & 7, iy = (c >> 3) & 7, iz = c & 7;
            const float lox = (float)ix * 0.125f, hix = lox + 0.125f;
            const float loy = (float)iy * 0.125f, hiy = loy + 0.125f;
            const float loz = (float)iz * 0.125f, hiz = loz + 0.125f;
            float ax = fmaxf(fmaxf(lox - px, px - hix), 0.0f);
            float ay = fmaxf(fmaxf(loy - py, py - hiy), 0.0f);
            float az = fmaxf(fmaxf(loz - pz, pz - hiz), 0.0f);
            const float lb2 = ax * ax + ay * ay + az * az;
            const float bmax = __uint_as_float((u32)(bkey[c] >> 32));
            dirty = !(lb2 >= bmax * 1.000004f); // conservative skip margin
        }
        u64 mask = __ballot(dirty);
        while (mask) {
            const int bit = __ffsll((unsigned long long)mask) - 1;
            mask &= mask - 1;
            const int c = (bit << 4) + w;
            const int start = (int)cellStart[c], end = (int)cellStart[c + 1];
            u64 bk = 0; float bx = 0.f, by = 0.f, bz = 0.f;
            for (int off = start; off < end; off += 64) {
                const int l = off + lane;
                if (l < end) {
                    const int id = ids[l];
                    const float gx = xb[3 * id], gy = xb[3 * id + 1], gz = xb[3 * id + 2];
                    const float dx = gx - px, dy = gy - py, dz = gz - pz;
                    const float d = __builtin_fmaf(dz, dz,
                                     __builtin_fmaf(dx, dx, dy * dy));
                    const float m = fminf(mind[id], d);
                    mind[id] = m;
                    const u64 key = ((u64)__float_as_uint(m) << 32) |
                                    (u64)(0xFFFFFFFFu - (u32)id);
                    if (key > bk) { bk = key; bx = gx; by = gy; bz = gz; }
                }
            }
#pragma unroll
            for (int o = 32; o; o >>= 1) {
                const u64 ok = __shfl_xor((unsigned long long)bk, o);
                const float ox = __shfl_xor(bx, o);
                const float oy = __shfl_xor(by, o);
                const float oz = __shfl_xor(bz, o);
                if (ok > bk) { bk = ok; bx = ox; by = oy; bz = oz; }
            }
            if (lane == 0) { bkey[c] = bk; bwx[c] = bx; bwy[c] = by; bwz[c] = bz; }
        }
        __syncthreads();                         // keys/winners current

        // ---- PHASE B: global argmax over 512 cached keys ----
        u64 k = 0; float wx = 0.f, wy = 0.f, wz = 0.f;
        if (t < NCELL) { k = bkey[t]; wx = bwx[t]; wy = bwy[t]; wz = bwz[t]; }
#pragma unroll
        for (int o = 32; o; o >>= 1) {
            const u64 ok = __shfl_xor((unsigned long long)k, o);
            const float ox = __shfl_xor(wx, o);
            const float oy = __shfl_xor(wy, o);
            const float oz = __shfl_xor(wz, o);
            if (ok > k) { k = ok; wx = ox; wy = oy; wz = oz; }
        }
        if (lane == 0) { redk[w] = k; redx[w] = wx; redy[w] = wy; redz[w] = wz; }
        __syncthreads();

        u64 fk = redk[0];
        float fx = redx[0], fy = redy[0], fz = redz[0];
#pragma unroll
        for (int j = 1; j < 16; ++j) {
            const u64 kk = redk[j];
            if (kk > fk) { fk = kk; fx = redx[j]; fy = redy[j]; fz = redz[j]; }
        }
        const int cur = (int)(0xFFFFFFFFu - (u32)(fk & 0xFFFFFFFFull));
        px = fx; py = fy; pz = fz;               // winner coords, no load

        if (t == 0) {
            oi[s] = (float)cur;
            op[(size_t)s * 3 + 0] = fx;
            op[(size_t)s * 3 + 1] = fy;
            op[(size_t)s * 3 + 2] = fz;
        }
    }
}

extern "C" void kernel_launch(void* const* d_in, const int* in_sizes, int n_in,
                              void* d_out, int out_size, void* d_ws, size_t ws_size,
                              hipStream_t stream) {
    const float* x = (const float*)d_in[0];
    const int B = in_sizes[0] / (FPS_N * 3);

    float* out_pts = (float*)d_out;
    float* out_idx = out_pts + (size_t)B * FPS_S * 3;
    u16* ids_ws = (u16*)d_ws;                    // B*32768*2 = 4 MB

    hipLaunchKernelGGL(FPSModel_80753975099708_kernel,
                       dim3(B), dim3(FPS_NT), 0, stream,
                       x, out_pts, out_idx, ids_ws);
}

// Round 12
// 4493.179 us; speedup vs baseline: 1.5293x; 1.5293x over previous
//
#include <hip/hip_runtime.h>

// FPS: B=64, N=32768, C=3, S=1024. One block per batch.
//
// Round-12: R11's exact culling scheme (validated bit-exact) with the
// memory pathology fixed. Prologue counting-sorts the cloud into d_ws as
// cell-contiguous float4 (x,y,z,orig_id_bits). Dirty-cell rescans are now
// coalesced dwordx4 streams; min_d is indexed by sorted slot (consecutive
// lanes -> consecutive LDS banks, conflict-free); dirty cells go into a
// worklist consumed by all 16 waves with stride-16 scheduling (balanced).
//
// Culling (validated R11, absmax=0): cell skipped iff
//   lb2(p, cellbox) >= bmax * 1.000004   (bmax = cell's cached max min_d)
// => every member's d >= min_d, fminf is a bit-exact no-op, cached key
// stays valid. Keys: u64 (val_bits<<32 | ~orig_idx): max = max val,
// tie -> min original index (= first occurrence). Empty cells key=0.
//
// Exactness (validated R3-R11): d = fma(dz,dz, fma(dx,dx, dy*dy)),
// fminf running min, first-occurrence argmax, order-independent combines.

typedef unsigned long long u64;
typedef unsigned int u32;
typedef unsigned short u16;

#define FPS_N   32768
#define FPS_S   1024
#define FPS_NT  1024
#define NCELL   512            // 8x8x8
#define PPT     (FPS_N / FPS_NT)

__device__ __forceinline__ int bin_of(float v) {
    int i = (int)(v * 8.0f);
    i = i < 0 ? 0 : (i > 7 ? 7 : i);
    // fix-up so the point provably lies in [i*0.125, (i+1)*0.125]
    if (v < (float)i * 0.125f) --i;
    if (v >= (float)(i + 1) * 0.125f) ++i;
    i = i < 0 ? 0 : (i > 7 ? 7 : i);
    return i;
}

__global__ __launch_bounds__(FPS_NT) void FPSModel_80753975099708_kernel(
    const float* __restrict__ x,   // [B, N, 3]
    float* __restrict__ out_pts,   // [B, S, 3]
    float* __restrict__ out_idx,   // [B, S] (indices as float values)
    float4* __restrict__ ws4)      // [B][N] cell-sorted (x,y,z,idbits)
{
#pragma clang fp contract(off)
    const int b = blockIdx.x;
    const int t = threadIdx.x;
    const int w = t >> 6;
    const int lane = t & 63;
    const float* __restrict__ xb = x + (size_t)b * FPS_N * 3;
    float* __restrict__ op = out_pts + (size_t)b * FPS_S * 3;
    float* __restrict__ oi = out_idx + (size_t)b * FPS_S;
    float4* __restrict__ srt = ws4 + (size_t)b * FPS_N;

    __shared__ float mind[FPS_N];          // 131072 B, indexed by sorted slot
    __shared__ u32  cellCnt[NCELL];        // hist, then scatter cursor
    __shared__ u32  cellStart[NCELL + 1];
    __shared__ u64  bkey[NCELL];           // cached per-cell max key
    __shared__ float bwx[NCELL], bwy[NCELL], bwz[NCELL];
    __shared__ u16  wl[2][NCELL];          // dirty worklists (double-buffered)
    __shared__ u32  nD[2];
    __shared__ u64  redk[16];
    __shared__ float redx[16], redy[16], redz[16];

    // ---- Prologue: counting sort into srt; init mind/bkey ----
    if (t < NCELL) cellCnt[t] = 0;
    if (t == 0) { nD[0] = 0; nD[1] = 0; }
    __syncthreads();

#pragma unroll
    for (int k = 0; k < PPT; ++k) {
        const int i = k * FPS_NT + t;
        mind[i] = __int_as_float(0x7f800000);      // +inf (slot-indexed later; all slots)
        const float gx = xb[3 * i], gy = xb[3 * i + 1], gz = xb[3 * i + 2];
        const int c = (bin_of(gx) << 6) | (bin_of(gy) << 3) | bin_of(gz);
        atomicAdd(&cellCnt[c], 1u);
    }
    __syncthreads();

    if (t == 0) {
        u32 acc = 0;
        for (int c = 0; c < NCELL; ++c) { cellStart[c] = acc; acc += cellCnt[c]; }
        cellStart[NCELL] = acc;                    // == FPS_N
    }
    __syncthreads();
    if (t < NCELL) cellCnt[t] = cellStart[t];      // scatter cursor
    __syncthreads();

#pragma unroll
    for (int k = 0; k < PPT; ++k) {
        const int i = k * FPS_NT + t;
        const float gx = xb[3 * i], gy = xb[3 * i + 1], gz = xb[3 * i + 2];
        const int c = (bin_of(gx) << 6) | (bin_of(gy) << 3) | bin_of(gz);
        const u32 slot = atomicAdd(&cellCnt[c], 1u);
        float4 q;
        q.x = gx; q.y = gy; q.z = gz; q.w = __uint_as_float((u32)i);
        srt[slot] = q;
    }
    if (t < NCELL) {
        bkey[t] = (cellStart[t + 1] > cellStart[t])
                      ? 0x7f80000000000000ULL      // +inf value -> dirty at s=1
                      : 0ULL;                      // empty: never dirty, never wins
        bwx[t] = 0.f; bwy[t] = 0.f; bwz[t] = 0.f;
    }

    // ---- Seed: point 0 (broadcast load) ----
    float px = xb[0], py = xb[1], pz = xb[2];
    if (t == 0) {
        oi[0] = 0.0f;
        op[0] = px; op[1] = py; op[2] = pz;
    }
    __syncthreads();

    for (int s = 1; s < FPS_S; ++s) {
        const int p = s & 1;
        // 1. prep next step's counter (last read ended before prev B2)
        if (t == 0) nD[1 - p] = 0;
        // 2. dirty test per cell; append to worklist
        if (t < NCELL) {
            const int ix = (t >> 6) & 7, iy = (t >> 3) & 7, iz = t & 7;
            const float lox = (float)ix * 0.125f;
            const float loy = (float)iy * 0.125f;
            const float loz = (float)iz * 0.125f;
            const float ax = fmaxf(fmaxf(lox - px, px - (lox + 0.125f)), 0.0f);
            const float ay = fmaxf(fmaxf(loy - py, py - (loy + 0.125f)), 0.0f);
            const float az = fmaxf(fmaxf(loz - pz, pz - (loz + 0.125f)), 0.0f);
            const float lb2 = ax * ax + ay * ay + az * az;
            const float bmax = __uint_as_float((u32)(bkey[t] >> 32));
            if (!(lb2 >= bmax * 1.000004f)) {
                wl[p][atomicAdd(&nD[p], 1u)] = (u16)t;
            }
        }
        __syncthreads();                           // B1: worklist ready

        // 4. process dirty cells, stride-16 over the worklist
        const int nd = (int)nD[p];
        for (int wi = w; wi < nd; wi += 16) {
            const int c = wl[p][wi];
            const int start = (int)cellStart[c], end = (int)cellStart[c + 1];
            u64 bk = 0; float bx = 0.f, by = 0.f, bz = 0.f;
            for (int off = start; off < end; off += 64) {
                const int l = off + lane;
                if (l < end) {
                    const float4 q = srt[l];       // coalesced dwordx4
                    const float dx = q.x - px;
                    const float dy = q.y - py;
                    const float dz = q.z - pz;
                    const float d = __builtin_fmaf(dz, dz,
                                     __builtin_fmaf(dx, dx, dy * dy));
                    const float m = fminf(mind[l], d);   // consecutive banks
                    mind[l] = m;
                    const u64 key = ((u64)__float_as_uint(m) << 32) |
                                    (u64)(0xFFFFFFFFu - __float_as_uint(q.w));
                    if (key > bk) { bk = key; bx = q.x; by = q.y; bz = q.z; }
                }
            }
#pragma unroll
            for (int o = 32; o; o >>= 1) {
                const u64 ok = __shfl_xor((unsigned long long)bk, o);
                const float ox = __shfl_xor(bx, o);
                const float oy = __shfl_xor(by, o);
                const float oz = __shfl_xor(bz, o);
                if (ok > bk) { bk = ok; bx = ox; by = oy; bz = oz; }
            }
            if (lane == 0) { bkey[c] = bk; bwx[c] = bx; bwy[c] = by; bwz[c] = bz; }
        }
        __syncthreads();                           // B2: keys/winners current

        // 6. reduce 512 cached keys (waves 0-7 carry data; 8-15 zeros)
        u64 k = 0; float wx = 0.f, wy = 0.f, wz = 0.f;
        if (t < NCELL) { k = bkey[t]; wx = bwx[t]; wy = bwy[t]; wz = bwz[t]; }
#pragma unroll
        for (int o = 32; o; o >>= 1) {
            const u64 ok = __shfl_xor((unsigned long long)k, o);
            const float ox = __shfl_xor(wx, o);
            const float oy = __shfl_xor(wy, o);
            const float oz = __shfl_xor(wz, o);
            if (ok > k) { k = ok; wx = ox; wy = oy; wz = oz; }
        }
        if (lane == 0) { redk[w] = k; redx[w] = wx; redy[w] = wy; redz[w] = wz; }
        __syncthreads();                           // B3: redk ready

        // 8. identical fold on every thread -> winner
        u64 fk = redk[0];
        float fx = redx[0], fy = redy[0], fz = redz[0];
#pragma unroll
        for (int j = 1; j < 16; ++j) {
            const u64 kk = redk[j];
            if (kk > fk) { fk = kk; fx = redx[j]; fy = redy[j]; fz = redz[j]; }
        }
        px = fx; py = fy; pz = fz;

        if (t == 0) {
            oi[s] = (float)(int)(0xFFFFFFFFu - (u32)(fk & 0xFFFFFFFFull));
            op[(size_t)s * 3 + 0] = fx;
            op[(size_t)s * 3 + 1] = fy;
            op[(size_t)s * 3 + 2] = fz;
        }
    }
}

extern "C" void kernel_launch(void* const* d_in, const int* in_sizes, int n_in,
                              void* d_out, int out_size, void* d_ws, size_t ws_size,
                              hipStream_t stream) {
    const float* x = (const float*)d_in[0];
    const int B = in_sizes[0] / (FPS_N * 3);

    float* out_pts = (float*)d_out;
    float* out_idx = out_pts + (size_t)B * FPS_S * 3;
    float4* ws4 = (float4*)d_ws;                   // needs B*32768*16 = 33.5 MB

    hipLaunchKernelGGL(FPSModel_80753975099708_kernel,
                       dim3(B), dim3(FPS_NT), 0, stream,
                       x, out_pts, out_idx, ws4);
}

// Round 13
// 3800.203 us; speedup vs baseline: 1.8082x; 1.1824x over previous
//
#include <hip/hip_runtime.h>

// FPS: B=64, N=32768, C=3, S=1024. One block per batch.
//
// Round-13: exact spatial culling (validated R11/R12, absmax=0) with the
// per-cell overhead stripped:
//  * 64 cells (4^3, box 0.25): dirty test = 1 lane/cell -> ONE __ballot,
//    computed redundantly per wave (no worklist, no barrier). j-th set bit
//    is scanned by wave j%16.
//  * key-only u64 butterflies (no coord carry); winner coords re-fetched
//    once per step via readfirstlane + scalar load.
//  * phase B: every thread folds the 64 cached keys (broadcast LDS reads).
//  * double-buffered bkey => ONE __syncthreads per step (step-s fold reads
//    buf p while step-s+1 scans write buf p^1; barrier induction makes
//    step-s+2 writes to p safe).
//  * 2-deep preload in the cell scan (coalesced float4 stream from d_ws,
//    cell-sorted by the prologue counting sort).
//
// Culling exactness (validated): skip cell iff lb2(p,box) >= bmax*1.000004
// => every member's d >= its min_d => fminf is a bit-exact no-op and the
// cached key stays valid. Keys: u64 (val_bits<<32 | ~orig_idx): max key =
// max value, tie -> min original index (= first occurrence). Empty cell
// key = 0 (bmax=0 -> never dirty, never wins).
// d = fma(dz,dz, fma(dx,dx, dy*dy)); contract(off) elsewhere.

typedef unsigned long long u64;
typedef unsigned int u32;

#define FPS_N   32768
#define FPS_S   1024
#define FPS_NT  1024
#define NCELL   64             // 4x4x4
#define PPT     (FPS_N / FPS_NT)

__device__ __forceinline__ int bin4(float v) {
    int i = (int)(v * 4.0f);
    i = i < 0 ? 0 : (i > 3 ? 3 : i);
    // fix-up so the point provably lies in [i*0.25, (i+1)*0.25]
    if (v < (float)i * 0.25f) --i;
    if (v >= (float)(i + 1) * 0.25f) ++i;
    i = i < 0 ? 0 : (i > 3 ? 3 : i);
    return i;
}

__global__ __launch_bounds__(FPS_NT) void FPSModel_80753975099708_kernel(
    const float* __restrict__ x,   // [B, N, 3]
    float* __restrict__ out_pts,   // [B, S, 3]
    float* __restrict__ out_idx,   // [B, S] (indices as float values)
    float4* __restrict__ ws4)      // [B][N] cell-sorted (x,y,z,idbits)
{
#pragma clang fp contract(off)
    const int b = blockIdx.x;
    const int t = threadIdx.x;
    const int w = t >> 6;
    const int lane = t & 63;
    const float* __restrict__ xb = x + (size_t)b * FPS_N * 3;
    float* __restrict__ op = out_pts + (size_t)b * FPS_S * 3;
    float* __restrict__ oi = out_idx + (size_t)b * FPS_S;
    float4* __restrict__ srt = ws4 + (size_t)b * FPS_N;

    __shared__ float mind[FPS_N];          // 131072 B, slot-indexed
    __shared__ u64  bkey[2][NCELL];        // double-buffered cell keys
    __shared__ u32  cellStart[NCELL + 1];
    __shared__ u32  cellCur[NCELL];

    // ---- Prologue: counting sort into srt; init mind/bkey ----
    if (t < NCELL) cellCur[t] = 0;
    __syncthreads();

#pragma unroll
    for (int k = 0; k < PPT; ++k) {
        const int i = k * FPS_NT + t;
        mind[i] = __int_as_float(0x7f800000);      // +inf
        const float gx = xb[3 * i], gy = xb[3 * i + 1], gz = xb[3 * i + 2];
        const int c = (bin4(gx) << 4) | (bin4(gy) << 2) | bin4(gz);
        atomicAdd(&cellCur[c], 1u);
    }
    __syncthreads();

    if (t == 0) {
        u32 acc = 0;
        for (int c = 0; c < NCELL; ++c) { cellStart[c] = acc; acc += cellCur[c]; }
        cellStart[NCELL] = acc;                    // == FPS_N
    }
    __syncthreads();
    if (t < NCELL) cellCur[t] = cellStart[t];      // scatter cursor
    __syncthreads();

#pragma unroll
    for (int k = 0; k < PPT; ++k) {
        const int i = k * FPS_NT + t;
        const float gx = xb[3 * i], gy = xb[3 * i + 1], gz = xb[3 * i + 2];
        const int c = (bin4(gx) << 4) | (bin4(gy) << 2) | bin4(gz);
        const u32 slot = atomicAdd(&cellCur[c], 1u);
        float4 q;
        q.x = gx; q.y = gy; q.z = gz; q.w = __uint_as_float((u32)i);
        srt[slot] = q;
    }
    if (t < NCELL) {
        bkey[0][t] = (cellStart[t + 1] > cellStart[t])
                         ? 0x7f80000000000000ULL   // +inf value -> dirty at s=1
                         : 0ULL;                   // empty: clean forever
    }

    // ---- Seed: point 0 ----
    float px = xb[0], py = xb[1], pz = xb[2];
    if (t == 0) {
        oi[0] = 0.0f;
        op[0] = px; op[1] = py; op[2] = pz;
    }
    __syncthreads();

    for (int s = 1; s < FPS_S; ++s) {
        const int p  = s & 1;                      // buffer written this step
        const int qb = p ^ 1;                      // buffer from last step

        // ---- dirty ballot: lane == cell (64 cells, one ballot) ----
        const int ix = (lane >> 4) & 3, iy = (lane >> 2) & 3, iz = lane & 3;
        const float lox = (float)ix * 0.25f;
        const float loy = (float)iy * 0.25f;
        const float loz = (float)iz * 0.25f;
        const float ax = fmaxf(fmaxf(lox - px, px - (lox + 0.25f)), 0.0f);
        const float ay = fmaxf(fmaxf(loy - py, py - (loy + 0.25f)), 0.0f);
        const float az = fmaxf(fmaxf(loz - pz, pz - (loz + 0.25f)), 0.0f);
        const float lb2 = ax * ax + ay * ay + az * az;
        const u64 prevk = bkey[qb][lane];
        const float bmax = __uint_as_float((u32)(prevk >> 32));
        const bool dirty = !(lb2 >= bmax * 1.000004f);
        const u64 mask = __ballot(dirty);

        // clean cells: carry key forward (wave 0 only; pre-barrier)
        if (w == 0 && !dirty) bkey[p][lane] = prevk;

        // ---- scan assigned dirty cells (j-th set bit -> wave j%16) ----
        u64 mrem = mask;
        int j = 0;
        while (mrem) {
            const int c = __ffsll((unsigned long long)mrem) - 1;
            mrem &= mrem - 1;
            if ((j & 15) == w) {
                const int end = (int)cellStart[c + 1];
                int off = (int)cellStart[c] + lane;
                u64 bk = 0;
                float4 q0;
                if (off < end) q0 = srt[off];          // preload
                while (off < end) {
                    const int off2 = off + 64;
                    float4 q1;
                    if (off2 < end) q1 = srt[off2];    // next in flight
                    const float dx = q0.x - px;
                    const float dy = q0.y - py;
                    const float dz = q0.z - pz;
                    const float d = __builtin_fmaf(dz, dz,
                                     __builtin_fmaf(dx, dx, dy * dy));
                    const float m = fminf(mind[off], d);
                    mind[off] = m;
                    const u64 key = ((u64)__float_as_uint(m) << 32) |
                                    (u64)(0xFFFFFFFFu - __float_as_uint(q0.w));
                    if (key > bk) bk = key;
                    q0 = q1;
                    off = off2;
                }
                // key-only butterfly (2 shuffle-words per level)
#pragma unroll
                for (int o = 32; o; o >>= 1) {
                    const u64 ok = __shfl_xor((unsigned long long)bk, o);
                    if (ok > bk) bk = ok;
                }
                if (lane == 0) bkey[p][c] = bk;
            }
            ++j;
        }
        __syncthreads();                           // ONE barrier per step

        // ---- phase B: every thread folds the 64 cached keys ----
        u64 fk = bkey[p][0];
#pragma unroll
        for (int jj = 1; jj < NCELL; ++jj) {
            const u64 kk = bkey[p][jj];
            if (kk > fk) fk = kk;
        }
        const int cur = (int)(0xFFFFFFFFu - (u32)(fk & 0xFFFFFFFFull));

        // winner coords: uniform -> scalar loads through constant cache
        const int curU = __builtin_amdgcn_readfirstlane(cur);
        px = xb[3 * curU + 0];
        py = xb[3 * curU + 1];
        pz = xb[3 * curU + 2];

        if (t == 0) {
            oi[s] = (float)cur;
            op[(size_t)s * 3 + 0] = px;
            op[(size_t)s * 3 + 1] = py;
            op[(size_t)s * 3 + 2] = pz;
        }
    }
}

extern "C" void kernel_launch(void* const* d_in, const int* in_sizes, int n_in,
                              void* d_out, int out_size, void* d_ws, size_t ws_size,
                              hipStream_t stream) {
    const float* x = (const float*)d_in[0];
    const int B = in_sizes[0] / (FPS_N * 3);

    float* out_pts = (float*)d_out;
    float* out_idx = out_pts + (size_t)B * FPS_S * 3;
    float4* ws4 = (float4*)d_ws;                   // needs B*32768*16 = 33.5 MB

    hipLaunchKernelGGL(FPSModel_80753975099708_kernel,
                       dim3(B), dim3(FPS_NT), 0, stream,
                       x, out_pts, out_idx, ws4);
}